// Round 1
// baseline (124.513 us; speedup 1.0000x reference)
//
#include <hip/hip_runtime.h>

typedef __bf16 bf16_t;
typedef __bf16 bf16x8 __attribute__((ext_vector_type(8)));
typedef bf16x8 bf16x8u __attribute__((aligned(8)));   // 8B-aligned vector load
typedef __bf16 bf16x4 __attribute__((ext_vector_type(4)));
typedef float f32x4 __attribute__((ext_vector_type(4)));

#define HH 96
#define WW 96
#define CC 128
#define HD 32
#define TOK (HH * WW)      // 9216
#define PLANE (TOK * CC)
#define KW 7

// bf16 weight slab (ws): qkv, proj, fc1, fc2
#define W_QKV  0
#define W_PROJ 49152
#define W_FC1  65536
#define W_FC2  131072
#define W_TOT  196608

#define PATCH 10            // patch rows
#define PCW 16              // patch col window (padded, 8-aligned loads)
#define PK 160              // P columns = 10 rows x 16 cols (=5*32, no pad)
#define PSTR 168            // P row stride (bf16): 2-way bank free
#define STR 136             // o_s/x0s row stride (bf16)
#define H1S 520

// K2 LDS layout (bf16 elements)
#define L_P    0            // Pbuf 4*16*PSTR = 10752 ele; h1s overlays (8320)
#define L_OS   10752        // o_s 16*STR
#define L_X0   12928        // x0s 16*STR
#define L_TOT  15104        // 30208 B -> 3 blocks/CU

// fp32 -> bf16x8
__device__ __forceinline__ bf16x8 cvt8(const float* __restrict__ p) {
    const f32x4 a = *(const f32x4*)p;
    const f32x4 b = *(const f32x4*)(p + 4);
    bf16x8 r;
    r[0] = (bf16_t)a[0]; r[1] = (bf16_t)a[1]; r[2] = (bf16_t)a[2]; r[3] = (bf16_t)a[3];
    r[4] = (bf16_t)b[0]; r[5] = (bf16_t)b[1]; r[6] = (bf16_t)b[2]; r[7] = (bf16_t)b[3];
    return r;
}

// NT-tile MFMA strip (bf16 A/W, K-contiguous rows, at tile origin).
// A-frag: lane holds A[lane&15][(lane>>4)*8+j]; B-frag: W[t*16+(lane&15)][...]
// C/D: reg r -> row (lane>>4)*4+r, col t*16+(lane&15)
template <int NT>
__device__ __forceinline__ void mmaN(const bf16_t* __restrict__ A, int lda,
                                     const bf16_t* __restrict__ W, int ldb,
                                     int K, f32x4* acc) {
    const int lane = threadIdx.x & 63;
    const bf16_t* ap = A + (lane & 15) * lda + ((lane >> 4) * 8);
    const bf16_t* bp = W + (lane & 15) * ldb + ((lane >> 4) * 8);
    for (int k0 = 0; k0 < K; k0 += 32) {
        bf16x8 a = *(const bf16x8*)(ap + k0);
#pragma unroll
        for (int t = 0; t < NT; t++) {
            bf16x8 b = *(const bf16x8*)(bp + t * 16 * ldb + k0);
            acc[t] = __builtin_amdgcn_mfma_f32_16x16x32_bf16(a, b, acc[t], 0, 0, 0);
        }
    }
}

// K0: cvt x + all 4 weight mats -> bf16.
__global__ __launch_bounds__(256) void k_prep(const float* __restrict__ x,
                                              const float* __restrict__ qkv_w,
                                              const float* __restrict__ proj_w,
                                              const float* __restrict__ fc1_w,
                                              const float* __restrict__ fc2_w,
                                              bf16_t* __restrict__ xb,
                                              bf16_t* __restrict__ wb) {
    const int idx = blockIdx.x * 256 + threadIdx.x;
    const int NX = PLANE / 4;          // 294912 x-chunks
    const float* src;
    bf16_t* dst;
    int base;
    if (idx < NX) {                    // x -> xb
        base = idx * 4; src = x + base; dst = xb + base;
    } else {                           // weights -> slab
        base = (idx - NX) * 4;
        if (base >= W_TOT) return;
        dst = wb + base;
        if (base < W_PROJ)     src = qkv_w  + base;
        else if (base < W_FC1) src = proj_w + (base - W_PROJ);
        else if (base < W_FC2) src = fc1_w  + (base - W_FC1);
        else                   src = fc2_w  + (base - W_FC2);
    }
    const f32x4 a = *(const f32x4*)src;
    bf16x4 r;
    r[0] = (bf16_t)a[0]; r[1] = (bf16_t)a[1]; r[2] = (bf16_t)a[2]; r[3] = (bf16_t)a[3];
    *(bf16x4*)dst = r;
}

// K1: qkv = xb @ qkv_w.T + b. q/k written row-major [tok][128];
// v written TRANSPOSED vt[ch][tok] (per-wave LDS transpose) for PV vec-gathers.
__global__ __launch_bounds__(256) void k_qkv(const bf16_t* __restrict__ xb,
                                             const bf16_t* __restrict__ wb,
                                             const float* __restrict__ bias,
                                             bf16_t* __restrict__ qb,
                                             bf16_t* __restrict__ kb,
                                             bf16_t* __restrict__ vt) {
    __shared__ __align__(16) bf16_t vtile[2 * 64 * 24];   // 2 v-waves x 64ch x 16tok (stride 24)
    const int wid = blockIdx.x * 4 + (threadIdx.x >> 6);   // 3456 waves
    const int m0 = (wid / 6) * 16;
    const int n0 = (wid % 6) * 64;
    const int lane = threadIdx.x & 63;
    const int g = lane >> 4, li = lane & 15;
    f32x4 acc[4] = {};
    mmaN<4>(xb + m0 * CC, CC, wb + W_QKV + n0 * CC, CC, CC, acc);
    if (n0 < 256) {                    // q / k: row-major scalar stores
#pragma unroll
        for (int t = 0; t < 4; t++) {
            const int n = n0 + t * 16 + li;
            const float bb = bias[n];
            const int c = n & 127;
            bf16_t* dst = (n >> 7) ? kb : qb;
#pragma unroll
            for (int r = 0; r < 4; r++)
                dst[(m0 + g * 4 + r) * CC + c] = (bf16_t)(acc[t][r] + bb);
        }
    } else {                           // v: transpose 16tok x 64ch tile via LDS
        const int cw = n0 - 256;       // 0 or 64
        bf16_t* tile = vtile + (cw >> 6) * (64 * 24);
#pragma unroll
        for (int t = 0; t < 4; t++) {
            const int n = n0 + t * 16 + li;
            const float bb = bias[n];
#pragma unroll
            for (int r = 0; r < 4; r++)
                tile[(t * 16 + li) * 24 + g * 4 + r] = (bf16_t)(acc[t][r] + bb);
        }
        asm volatile("s_waitcnt lgkmcnt(0)" ::: "memory");  // wave-local LDS visibility
        const bf16x8 u0 = *(const bf16x8*)(tile + lane * 24);
        const bf16x8 u1 = *(const bf16x8*)(tile + lane * 24 + 8);
        bf16_t* dst = vt + (cw + lane) * TOK + m0;
        *(bf16x8*)dst = u0;
        *(bf16x8*)(dst + 8) = u1;
    }
}

// ===========================================================================
// K2: attn + proj + MLP per 4x4-token tile. 576 blocks x 256, one wave/head.
// P indexed as 10x16 padded patch (K=160): PV B-frags are 16B vector loads
// from vt; K-phase offsets computed arithmetically (no voff table/barrier).
// ===========================================================================
__global__ __launch_bounds__(256, 3) void k_attn_mlp(
        const bf16_t* __restrict__ qb, const bf16_t* __restrict__ kg,
        const bf16_t* __restrict__ vt, const bf16_t* __restrict__ wb,
        const float* __restrict__ proj_b, const float* __restrict__ fc1_b,
        const float* __restrict__ fc2_b,  float* __restrict__ out) {
    __shared__ __align__(16) bf16_t smem[L_TOT];
    bf16_t* Pbuf = smem + L_P;
    bf16_t* o_s  = smem + L_OS;
    bf16_t* x0s  = smem + L_X0;
    bf16_t* h1s  = smem + L_P;          // overlays Pbuf after barrier B2

    const int tid = threadIdx.x;
    const int w = tid >> 6, lane = tid & 63;
    const int g = lane >> 4, li = lane & 15;
    const int bid = blockIdx.x;
    const int i0 = (bid / 24) * 4, j0 = (bid % 24) * 4;
    const int pr0 = min(max(i0 - 3, 0), HH - PATCH);
    const int pc0 = min(max(j0 - 4, 0), WW - PCW);   // multiple of 4
    const int ch = w * HD;

    // ---- attn phase 1: logits[16][160] = Q @ K^T (computed-offset gathers) ----
    f32x4 lg[10];
    {
        const int qi = i0 + (li >> 2), qj = j0 + (li & 3);
        const bf16x8 aq = *(const bf16x8*)(qb + (qi * WW + qj) * CC + ch + g * 8);
#pragma unroll
        for (int t = 0; t < 10; t++) {
            const int tok = (pr0 + t) * WW + pc0 + li;
            const bf16x8 bk = *(const bf16x8*)(kg + tok * CC + ch + g * 8);
            lg[t] = __builtin_amdgcn_mfma_f32_16x16x32_bf16(aq, bk, (f32x4){0.f,0.f,0.f,0.f}, 0, 0, 0);
        }
    }
    // ---- mask + register softmax ----
    int lr[4], lc[4];
#pragma unroll
    for (int r = 0; r < 4; r++) {
        const int m = g * 4 + r;
        const int i = i0 + (m >> 2), j = j0 + (m & 3);
        lr[r] = min(max(i - 3, 0), HH - KW) - pr0;
        lc[r] = min(max(j - 3, 0), WW - KW) - pc0;
    }
    const float scale = 0.17677669529663687f;   // 1/sqrt(32)
#pragma unroll
    for (int t = 0; t < 10; t++) {
#pragma unroll
        for (int r = 0; r < 4; r++) {
            const bool valid = ((unsigned)(t - lr[r]) <= 6u) &&
                               ((unsigned)(li - lc[r]) <= 6u);
            lg[t][r] = valid ? lg[t][r] * scale : -1e30f;
        }
    }
    f32x4 mx = lg[0], sm;
#pragma unroll
    for (int t = 1; t < 10; t++)
#pragma unroll
        for (int r = 0; r < 4; r++) mx[r] = fmaxf(mx[r], lg[t][r]);
#pragma unroll
    for (int off = 8; off; off >>= 1)
#pragma unroll
        for (int r = 0; r < 4; r++) mx[r] = fmaxf(mx[r], __shfl_xor(mx[r], off));
#pragma unroll
    for (int r = 0; r < 4; r++) sm[r] = 0.f;
#pragma unroll
    for (int t = 0; t < 10; t++)
#pragma unroll
        for (int r = 0; r < 4; r++) {
            lg[t][r] = __expf(lg[t][r] - mx[r]);
            sm[r] += lg[t][r];
        }
#pragma unroll
    for (int off = 8; off; off >>= 1)
#pragma unroll
        for (int r = 0; r < 4; r++) sm[r] += __shfl_xor(sm[r], off);
#pragma unroll
    for (int r = 0; r < 4; r++) sm[r] = 1.f / sm[r];

    // ---- P bf16 -> per-wave Pbuf (all 160 cols defined; invalid = 0) ----
    bf16_t* Pw = Pbuf + w * 16 * PSTR;
#pragma unroll
    for (int t = 0; t < 10; t++)
#pragma unroll
        for (int r = 0; r < 4; r++)
            Pw[(g * 4 + r) * PSTR + t * 16 + li] = (bf16_t)(lg[t][r] * sm[r]);

    // ---- attn phase 2: O[16][32] = P @ V^T (vectorized vt gathers) ----
    f32x4 oA[2] = {};
#pragma unroll
    for (int ks0 = 0; ks0 < PK; ks0 += 32) {
        const int kb_ = ks0 + g * 8;
        const int tokb = (pr0 + (kb_ >> 4)) * WW + pc0 + (kb_ & 15);
        const bf16x8 a = *(const bf16x8*)(Pw + li * PSTR + ks0 + g * 8);
#pragma unroll
        for (int t2 = 0; t2 < 2; t2++) {
            const int cb = ch + t2 * 16 + li;
            const bf16x8 b = *(const bf16x8u*)(vt + cb * TOK + tokb);
            oA[t2] = __builtin_amdgcn_mfma_f32_16x16x32_bf16(a, b, oA[t2], 0, 0, 0);
        }
    }
#pragma unroll
    for (int t2 = 0; t2 < 2; t2++)
#pragma unroll
        for (int r = 0; r < 4; r++)
            o_s[(g * 4 + r) * STR + ch + t2 * 16 + li] = (bf16_t)oA[t2][r];
    __syncthreads();                    // B2: o_s ready; Pbuf dead

    // ---- proj: x0s[16][128] = o @ proj_w^T + b ----
    {
        f32x4 acc[2] = {};
        mmaN<2>(o_s, STR, wb + W_PROJ + (w * 32) * CC, CC, CC, acc);
#pragma unroll
        for (int t = 0; t < 2; t++) {
            const int n = w * 32 + t * 16 + li;
            const float bb = proj_b[n];
#pragma unroll
            for (int r = 0; r < 4; r++)
                x0s[(g * 4 + r) * STR + n] = (bf16_t)(acc[t][r] + bb);
        }
    }
    __syncthreads();                    // B3: x0s ready

    // ---- fc1 + gelu: h1s[16][512] ----
    {
        f32x4 acc[8] = {};
        mmaN<8>(x0s, STR, wb + W_FC1 + (w * 128) * CC, CC, CC, acc);
#pragma unroll
        for (int t = 0; t < 8; t++) {
            const int n = w * 128 + t * 16 + li;
            const float bb = fc1_b[n];
#pragma unroll
            for (int r = 0; r < 4; r++) {
                const int m = g * 4 + r;
                const float xv = acc[t][r] + bb;
                const float u = 0.7978845608028654f * (xv + 0.044715f * xv * xv * xv);
                const float e = __expf(2.f * u);
                const float gg = 0.5f * xv * (2.f - 2.f / (e + 1.f));
                h1s[m * H1S + n] = (bf16_t)gg;
            }
        }
    }
    __syncthreads();                    // B4: h1s ready

    // ---- fc2: fp32 out over the tile's own rows ----
    {
        f32x4 acc[2] = {};
        mmaN<2>(h1s, H1S, wb + W_FC2 + (w * 32) * (4 * CC), 4 * CC, 4 * CC, acc);
#pragma unroll
        for (int t = 0; t < 2; t++) {
            const int n = w * 32 + t * 16 + li;
            const float bb = fc2_b[n];
#pragma unroll
            for (int r = 0; r < 4; r++) {
                const int m = g * 4 + r;
                const int i = i0 + (m >> 2), j = j0 + (m & 3);
                float xv = acc[t][r] + bb;
                xv = fminf(fmaxf(xv, -1e4f), 1e4f);   // diagnostic clamp
                out[(i * WW + j) * CC + n] = xv;
            }
        }
    }
}

extern "C" void kernel_launch(void* const* d_in, const int* in_sizes, int n_in,
                              void* d_out, int out_size, void* d_ws, size_t ws_size,
                              hipStream_t stream) {
    const float* x      = (const float*)d_in[0];
    const float* qkv_w  = (const float*)d_in[1];
    const float* qkv_b  = (const float*)d_in[2];
    const float* proj_w = (const float*)d_in[3];
    const float* proj_b = (const float*)d_in[4];
    const float* fc1_w  = (const float*)d_in[5];
    const float* fc1_b  = (const float*)d_in[6];
    const float* fc2_w  = (const float*)d_in[7];
    const float* fc2_b  = (const float*)d_in[8];

    bf16_t* ws = (bf16_t*)d_ws;
    bf16_t* wb = ws;                    // bf16 weight slab
    bf16_t* xb = ws + W_TOT;            // x bf16 plane
    bf16_t* qb = xb + PLANE;            // q plane [tok][128]
    bf16_t* kb = qb + PLANE;            // k plane [tok][128]
    bf16_t* vt = kb + PLANE;            // v TRANSPOSED plane [128][tok]
    float* out = (float*)d_out;

    k_prep    <<<1344, 256, 0, stream>>>(x, qkv_w, proj_w, fc1_w, fc2_w, xb, wb);
    k_qkv     <<<864,  256, 0, stream>>>(xb, wb, qkv_b, qb, kb, vt);
    k_attn_mlp<<<576,  256, 0, stream>>>(qb, kb, vt, wb,
                                         proj_b, fc1_b, fc2_b, out);
}

// Round 3
// 123.270 us; speedup vs baseline: 1.0101x; 1.0101x over previous
//
#include <hip/hip_runtime.h>

typedef __bf16 bf16_t;
typedef __bf16 bf16x8 __attribute__((ext_vector_type(8)));
typedef __bf16 bf16x4 __attribute__((ext_vector_type(4)));
typedef float f32x4 __attribute__((ext_vector_type(4)));
typedef int   i32x4 __attribute__((ext_vector_type(4)));

#define HH 96
#define WW 96
#define CC 128
#define HD 32
#define TOK (HH * WW)      // 9216
#define PLANE (TOK * CC)
#define KW 7

// bf16 weight slab (ws): qkv (unused), proj, fc1, fc2
#define W_QKV  0
#define W_PROJ 49152
#define W_FC1  65536
#define W_FC2  131072
#define W_TOT  196608

#define PATCH 10
#define PSZ 100
#define NPAD 112            // 7 N-tiles of 16
#define STR 136             // LDS row stride (bf16)
#define H1S 520

// K2 LDS layout (bf16 elements) — proven layout
#define L_P    0            // Pbuf 4*16*STR = 8704 ele -> h1s overlay (8320)
#define L_OS   8704         // o_s 16*STR
#define L_X0   10880        // x0s 16*STR
#define L_VOFF 13056        // 128 ints
#define L_TOT  13312        // 26624 B -> 3 blocks/CU

// f32 pointer -> bf16x8 fragment (two 16B loads + cvt)
__device__ __forceinline__ bf16x8 ld8f(const float* __restrict__ p) {
    const f32x4 a = *(const f32x4*)p;
    const f32x4 b = *(const f32x4*)(p + 4);
    bf16x8 r;
    r[0] = (bf16_t)a[0]; r[1] = (bf16_t)a[1]; r[2] = (bf16_t)a[2]; r[3] = (bf16_t)a[3];
    r[4] = (bf16_t)b[0]; r[5] = (bf16_t)b[1]; r[6] = (bf16_t)b[2]; r[7] = (bf16_t)b[3];
    return r;
}

// NT-tile MFMA strip (bf16 A/W, K-contiguous rows, at tile origin).
// A-frag: lane holds A[lane&15][(lane>>4)*8+j]; B-frag: W[t*16+(lane&15)][...]
// C/D: reg r -> row (lane>>4)*4+r, col t*16+(lane&15)
template <int NT>
__device__ __forceinline__ void mmaN(const bf16_t* __restrict__ A, int lda,
                                     const bf16_t* __restrict__ W, int ldb,
                                     int K, f32x4* acc) {
    const int lane = threadIdx.x & 63;
    const bf16_t* ap = A + (lane & 15) * lda + ((lane >> 4) * 8);
    const bf16_t* bp = W + (lane & 15) * ldb + ((lane >> 4) * 8);
    for (int k0 = 0; k0 < K; k0 += 32) {
        bf16x8 a = *(const bf16x8*)(ap + k0);
#pragma unroll
        for (int t = 0; t < NT; t++) {
            bf16x8 b = *(const bf16x8*)(bp + t * 16 * ldb + k0);
            acc[t] = __builtin_amdgcn_mfma_f32_16x16x32_bf16(a, b, acc[t], 0, 0, 0);
        }
    }
}

// ===========================================================================
// K1': fused prep+qkv. Blocks 0..863: qkv = x @ qkv_w.T + b with INLINE
// f32->bf16 fragment conversion (no xb plane, no separate prep pass).
// Blocks 864..911: convert proj/fc1/fc2 weights -> bf16 slab for K2.
// ===========================================================================
__global__ __launch_bounds__(256) void k_qkv2(const float* __restrict__ x,
                                              const float* __restrict__ qkv_w,
                                              const float* __restrict__ proj_w,
                                              const float* __restrict__ fc1_w,
                                              const float* __restrict__ fc2_w,
                                              const float* __restrict__ bias,
                                              bf16_t* __restrict__ qb,
                                              bf16_t* __restrict__ kb,
                                              bf16_t* __restrict__ vb,
                                              bf16_t* __restrict__ wb) {
    const int nb = blockIdx.x;
    const int tid = threadIdx.x;

    if (nb >= 864) {                   // weight-slab conversion: 48 blocks
        const int idx0 = (nb - 864) * 256 + tid;     // 0..12287
#pragma unroll
        for (int r = 0; r < 3; r++) {
            const int base = W_PROJ + (idx0 + r * 12288) * 4;   // < W_TOT
            const float* src;
            if (base < W_FC1)      src = proj_w + (base - W_PROJ);
            else if (base < W_FC2) src = fc1_w  + (base - W_FC1);
            else                   src = fc2_w  + (base - W_FC2);
            const f32x4 a = *(const f32x4*)src;
            bf16x4 rv;
            rv[0] = (bf16_t)a[0]; rv[1] = (bf16_t)a[1];
            rv[2] = (bf16_t)a[2]; rv[3] = (bf16_t)a[3];
            *(bf16x4*)(wb + base) = rv;
        }
        return;
    }

    const int wid = nb * 4 + (tid >> 6);   // 0..3455
    const int m0 = (wid / 6) * 16;
    const int n0 = (wid % 6) * 64;
    const int lane = tid & 63;
    const int g = lane >> 4, li = lane & 15;

    f32x4 acc[4] = {};
    {
        const float* ap = x + (m0 + li) * CC + g * 8;
        const float* bp = qkv_w + (n0 + li) * CC + g * 8;
#pragma unroll
        for (int k0 = 0; k0 < CC; k0 += 32) {
            const bf16x8 a = ld8f(ap + k0);
#pragma unroll
            for (int t = 0; t < 4; t++) {
                const bf16x8 b = ld8f(bp + t * 16 * CC + k0);
                acc[t] = __builtin_amdgcn_mfma_f32_16x16x32_bf16(a, b, acc[t], 0, 0, 0);
            }
        }
    }
#pragma unroll
    for (int t = 0; t < 4; t++) {
        const int n = n0 + t * 16 + li;
        const float bb = bias[n];
        const int part = n >> 7, c = n & 127;
        bf16_t* dst = (part == 0) ? qb : (part == 1) ? kb : vb;
#pragma unroll
        for (int r = 0; r < 4; r++)
            dst[(m0 + g * 4 + r) * CC + c] = (bf16_t)(acc[t][r] + bb);
    }
}

// ===========================================================================
// K2: attn + proj + MLP per 4x4-token tile. 576 blocks x 256, one wave/head.
// (proven 118 us body, unchanged)
// ===========================================================================
__global__ __launch_bounds__(256, 3) void k_attn_mlp(
        const bf16_t* __restrict__ qb, const bf16_t* __restrict__ kg,
        const bf16_t* __restrict__ vg, const bf16_t* __restrict__ wb,
        const float* __restrict__ proj_b, const float* __restrict__ fc1_b,
        const float* __restrict__ fc2_b,  float* __restrict__ out) {
    __shared__ __align__(16) bf16_t smem[L_TOT];
    bf16_t* Pbuf = smem + L_P;
    bf16_t* o_s  = smem + L_OS;
    bf16_t* x0s  = smem + L_X0;
    bf16_t* h1s  = smem + L_P;          // overlays Pbuf after barrier 2
    int*    voff = (int*)(smem + L_VOFF);

    const int tid = threadIdx.x;
    const int w = tid >> 6, lane = tid & 63;
    const int g = lane >> 4, li = lane & 15;
    const int bid = blockIdx.x;
    const int i0 = (bid / 24) * 4, j0 = (bid % 24) * 4;
    const int pr0 = min(max(i0 - 3, 0), HH - PATCH);
    const int pc0 = min(max(j0 - 3, 0), WW - PATCH);
    const int ch = w * HD;

    if (tid < 128) {
        const int p = min(tid, PSZ - 1);
        const int pi = p / 10, pj = p - 10 * pi;
        voff[tid] = ((pr0 + pi) * WW + pc0 + pj) * CC;
    }
    __syncthreads();                    // B1: voff ready

    // ---- attn phase 1: logits[16][112] = Q @ K^T ----
    f32x4 lg[7];
    {
        const int qi = i0 + (li >> 2), qj = j0 + (li & 3);
        const bf16x8 aq = *(const bf16x8*)(qb + (qi * WW + qj) * CC + ch + g * 8);
#pragma unroll
        for (int t = 0; t < 7; t++) {
            const bf16x8 bk = *(const bf16x8*)(kg + voff[t * 16 + li] + ch + g * 8);
            lg[t] = __builtin_amdgcn_mfma_f32_16x16x32_bf16(aq, bk, (f32x4){0.f,0.f,0.f,0.f}, 0, 0, 0);
        }
    }
    // ---- mask + register softmax ----
    int lr[4], lc[4];
#pragma unroll
    for (int r = 0; r < 4; r++) {
        const int m = g * 4 + r;
        const int i = i0 + (m >> 2), j = j0 + (m & 3);
        lr[r] = min(max(i - 3, 0), HH - KW) - pr0;
        lc[r] = min(max(j - 3, 0), WW - KW) - pc0;
    }
    const float scale = 0.17677669529663687f;   // 1/sqrt(32)
#pragma unroll
    for (int t = 0; t < 7; t++) {
        const int col = t * 16 + li;
        const int pi = col / 10, pj = col - 10 * pi;
#pragma unroll
        for (int r = 0; r < 4; r++) {
            const bool valid = (col < PSZ) &&
                               ((unsigned)(pi - lr[r]) <= 6u) &&
                               ((unsigned)(pj - lc[r]) <= 6u);
            lg[t][r] = valid ? lg[t][r] * scale : -1e30f;
        }
    }
    f32x4 mx = lg[0], sm;
#pragma unroll
    for (int t = 1; t < 7; t++)
#pragma unroll
        for (int r = 0; r < 4; r++) mx[r] = fmaxf(mx[r], lg[t][r]);
#pragma unroll
    for (int off = 8; off; off >>= 1)
#pragma unroll
        for (int r = 0; r < 4; r++) mx[r] = fmaxf(mx[r], __shfl_xor(mx[r], off));
#pragma unroll
    for (int r = 0; r < 4; r++) sm[r] = 0.f;
#pragma unroll
    for (int t = 0; t < 7; t++)
#pragma unroll
        for (int r = 0; r < 4; r++) {
            lg[t][r] = __expf(lg[t][r] - mx[r]);
            sm[r] += lg[t][r];
        }
#pragma unroll
    for (int off = 8; off; off >>= 1)
#pragma unroll
        for (int r = 0; r < 4; r++) sm[r] += __shfl_xor(sm[r], off);
#pragma unroll
    for (int r = 0; r < 4; r++) sm[r] = 1.f / sm[r];

    // ---- P bf16 -> per-wave Pbuf (cols 112..127 zeroed) ----
    bf16_t* Pw = Pbuf + w * 16 * STR;
#pragma unroll
    for (int t = 0; t < 7; t++)
#pragma unroll
        for (int r = 0; r < 4; r++)
            Pw[(g * 4 + r) * STR + t * 16 + li] = (bf16_t)(lg[t][r] * sm[r]);
    *(bf16x4*)(Pw + (lane >> 2) * STR + NPAD + (lane & 3) * 4) = (bf16x4){0,0,0,0};

    // ---- attn phase 2: O[16][32] = P @ V^T (voff-table gathers) ----
    f32x4 oA[2] = {};
#pragma unroll
    for (int ks0 = 0; ks0 < 128; ks0 += 32) {
        const bf16x8 a = *(const bf16x8*)(Pw + li * STR + ks0 + g * 8);
        const i32x4 o0 = *(const i32x4*)&voff[ks0 + g * 8];
        const i32x4 o1 = *(const i32x4*)&voff[ks0 + g * 8 + 4];
#pragma unroll
        for (int t2 = 0; t2 < 2; t2++) {
            const int cb = ch + t2 * 16 + li;
            bf16x8 b;
            b[0] = vg[o0[0] + cb]; b[1] = vg[o0[1] + cb];
            b[2] = vg[o0[2] + cb]; b[3] = vg[o0[3] + cb];
            b[4] = vg[o1[0] + cb]; b[5] = vg[o1[1] + cb];
            b[6] = vg[o1[2] + cb]; b[7] = vg[o1[3] + cb];
            oA[t2] = __builtin_amdgcn_mfma_f32_16x16x32_bf16(a, b, oA[t2], 0, 0, 0);
        }
    }
#pragma unroll
    for (int t2 = 0; t2 < 2; t2++)
#pragma unroll
        for (int r = 0; r < 4; r++)
            o_s[(g * 4 + r) * STR + ch + t2 * 16 + li] = (bf16_t)oA[t2][r];
    __syncthreads();                    // B2: o_s ready; Pbuf dead

    // ---- proj: x0s[16][128] = o @ proj_w^T + b ----
    {
        f32x4 acc[2] = {};
        mmaN<2>(o_s, STR, wb + W_PROJ + (w * 32) * CC, CC, CC, acc);
#pragma unroll
        for (int t = 0; t < 2; t++) {
            const int n = w * 32 + t * 16 + li;
            const float bb = proj_b[n];
#pragma unroll
            for (int r = 0; r < 4; r++)
                x0s[(g * 4 + r) * STR + n] = (bf16_t)(acc[t][r] + bb);
        }
    }
    __syncthreads();                    // B3: x0s ready

    // ---- fc1 + gelu: h1s[16][512] ----
    {
        f32x4 acc[8] = {};
        mmaN<8>(x0s, STR, wb + W_FC1 + (w * 128) * CC, CC, CC, acc);
#pragma unroll
        for (int t = 0; t < 8; t++) {
            const int n = w * 128 + t * 16 + li;
            const float bb = fc1_b[n];
#pragma unroll
            for (int r = 0; r < 4; r++) {
                const int m = g * 4 + r;
                const float xv = acc[t][r] + bb;
                const float u = 0.7978845608028654f * (xv + 0.044715f * xv * xv * xv);
                const float e = __expf(2.f * u);
                const float gg = 0.5f * xv * (2.f - 2.f / (e + 1.f));
                h1s[m * H1S + n] = (bf16_t)gg;
            }
        }
    }
    __syncthreads();                    // B4: h1s ready

    // ---- fc2: fp32 out over the tile's own rows ----
    {
        f32x4 acc[2] = {};
        mmaN<2>(h1s, H1S, wb + W_FC2 + (w * 32) * (4 * CC), 4 * CC, 4 * CC, acc);
#pragma unroll
        for (int t = 0; t < 2; t++) {
            const int n = w * 32 + t * 16 + li;
            const float bb = fc2_b[n];
#pragma unroll
            for (int r = 0; r < 4; r++) {
                const int m = g * 4 + r;
                const int i = i0 + (m >> 2), j = j0 + (m & 3);
                float xv = acc[t][r] + bb;
                xv = fminf(fmaxf(xv, -1e4f), 1e4f);   // diagnostic clamp
                out[(i * WW + j) * CC + n] = xv;
            }
        }
    }
}

extern "C" void kernel_launch(void* const* d_in, const int* in_sizes, int n_in,
                              void* d_out, int out_size, void* d_ws, size_t ws_size,
                              hipStream_t stream) {
    const float* x      = (const float*)d_in[0];
    const float* qkv_w  = (const float*)d_in[1];
    const float* qkv_b  = (const float*)d_in[2];
    const float* proj_w = (const float*)d_in[3];
    const float* proj_b = (const float*)d_in[4];
    const float* fc1_w  = (const float*)d_in[5];
    const float* fc1_b  = (const float*)d_in[6];
    const float* fc2_w  = (const float*)d_in[7];
    const float* fc2_b  = (const float*)d_in[8];

    bf16_t* ws = (bf16_t*)d_ws;
    bf16_t* wb = ws;                    // bf16 weight slab
    bf16_t* qb = ws + W_TOT;            // q/k/v bf16 planes
    bf16_t* kb = qb + PLANE;
    bf16_t* vb = kb + PLANE;
    float* out = (float*)d_out;

    k_qkv2    <<<912, 256, 0, stream>>>(x, qkv_w, proj_w, fc1_w, fc2_w,
                                        qkv_b, qb, kb, vb, wb);
    k_attn_mlp<<<576, 256, 0, stream>>>(qb, kb, vb, wb,
                                        proj_b, fc1_b, fc2_b, out);
}